// Round 3
// baseline (423.560 us; speedup 1.0000x reference)
//
#include <hip/hip_runtime.h>
#include <math.h>

// ExpertGate — np.einsum-bitwise replication + double-buffered staging.
//
// CORRECTNESS CONTRACT (do not touch): per (token, expert) the dot product
// must be bitwise-identical to numpy's einsum float32
// sum_of_products_contig_two (SSE3 baseline, no FMA):
//   - 4 accumulator chains (k mod 4)
//   - k in groups of 16, quads within a group processed j = 3,2,1,0
//   - separate mul/add roundings (__fmul_rn/__fadd_rn, never contracted)
//   - final reduce (c0+c1)+(c2+c3); sigmoid = 1/(1+exp(-z)) in fp32 with
//     correctly-rounded fp32 exp (via double exp)
// Verified passing in round 2 (indices exact, weights absmax 2e-3).
//
// PERF CHANGES vs round 2 (scheduling only, bitwise-safe):
//   - Double-buffered Xs/Ws in LDS; ONE __syncthreads per K-round (was 2).
//   - Async-STAGE split (T14): next round's global loads are issued into
//     registers BEFORE the compute phase (compute hides the ~500cy HBM/L2
//     latency), ds_writes land after compute, before the barrier.
//   - Global pointers advance by += BK; LDS offsets are per-thread constants
//     folded into ds_read/ds_write immediates (kills address-calc VALU).
// Round-2 counters: dur 162us, VALUBusy 46% (floor 54.6us), stalls ~87us.

#define D_DIM 2048
#define E_DIM 64
#define TOPK 8
#define TM 32               // tokens per block
#define BK 64               // k staged per round (4 groups of 16)
#define NR (D_DIM / BK)     // 32 rounds
#define XS 68               // Xs row stride (floats): 16B-aligned, non-pow2
#define WS 68
#define SCS 65
#define XHALF (TM * XS)     // 2176 floats per X buffer
#define WHALF (E_DIM * WS)  // 4352 floats per W buffer

__global__ __launch_bounds__(256) void expert_gate_kernel(
    const float* __restrict__ x,      // (N, 2048)
    const float* __restrict__ w,      // (64, 2048)
    const float* __restrict__ bias,   // (64,)
    float* __restrict__ out,          // N*8 weights, then N*8 indices-as-float
    int N)
{
    __shared__ float Xs[2 * XHALF];   // 17.4 KB
    __shared__ float Ws[2 * WHALF];   // 34.8 KB
    __shared__ float Sc[TM * SCS];    //  8.3 KB   (total 60.5 KB -> 2 blocks/CU)

    const int t    = threadIdx.x;
    const int tx   = t & 15;          // experts tx + 16*e, e=0..3
    const int ty   = t >> 4;          // tokens  ty + 16*i, i=0..1
    const int tok0 = blockIdx.x * TM;
    const int lane = t & 63;
    const float my_bias = bias[lane];

    // ---- per-thread staging addresses (hoisted out of the K-loop) ----
    const int srow = t >> 4;          // 0..15
    const int scol = (t & 15) << 2;   // 0,4,..,60
    const float* xp0 = &x[(size_t)(tok0 + srow) * D_DIM + scol];
    const float* xp1 = &x[(size_t)(tok0 + 16 + srow) * D_DIM + scol];
    const float* wp  = &w[(size_t)srow * D_DIM + scol];
    const int xw0 = srow * XS + scol;            // LDS write offsets (floats)
    const int xw1 = (srow + 16) * XS + scol;
    const int ww0 = srow * WS + scol;

    // c[token][expert][chain l]; chain l accumulates k % 4 == l
    float c[2][4][4];
    #pragma unroll
    for (int i = 0; i < 2; ++i)
        #pragma unroll
        for (int e = 0; e < 4; ++e)
            #pragma unroll
            for (int l = 0; l < 4; ++l) c[i][e][l] = 0.f;

    // ---- prologue: stage round 0 into buffer 0 ----
    float4 sx0 = *reinterpret_cast<const float4*>(xp0);
    float4 sx1 = *reinterpret_cast<const float4*>(xp1);
    float4 sw0 = *reinterpret_cast<const float4*>(wp);
    float4 sw1 = *reinterpret_cast<const float4*>(wp + 16 * D_DIM);
    float4 sw2 = *reinterpret_cast<const float4*>(wp + 32 * D_DIM);
    float4 sw3 = *reinterpret_cast<const float4*>(wp + 48 * D_DIM);
    xp0 += BK; xp1 += BK; wp += BK;
    *reinterpret_cast<float4*>(&Xs[xw0]) = sx0;
    *reinterpret_cast<float4*>(&Xs[xw1]) = sx1;
    *reinterpret_cast<float4*>(&Ws[ww0]) = sw0;
    *reinterpret_cast<float4*>(&Ws[ww0 + 16 * WS]) = sw1;
    *reinterpret_cast<float4*>(&Ws[ww0 + 32 * WS]) = sw2;
    *reinterpret_cast<float4*>(&Ws[ww0 + 48 * WS]) = sw3;
    __syncthreads();

    for (int s = 0; s < NR; ++s) {
        const int cur = s & 1;
        const float* Xc = Xs + cur * XHALF;
        const float* Wc = Ws + cur * WHALF;

        // ---- issue next round's global loads (no wait: hides under compute)
        if (s + 1 < NR) {
            sx0 = *reinterpret_cast<const float4*>(xp0);
            sx1 = *reinterpret_cast<const float4*>(xp1);
            sw0 = *reinterpret_cast<const float4*>(wp);
            sw1 = *reinterpret_cast<const float4*>(wp + 16 * D_DIM);
            sw2 = *reinterpret_cast<const float4*>(wp + 32 * D_DIM);
            sw3 = *reinterpret_cast<const float4*>(wp + 48 * D_DIM);
            xp0 += BK; xp1 += BK; wp += BK;
        }

        // ---- compute: 4 groups of 16 k, quads within group in order 3,2,1,0
        #pragma unroll
        for (int g = 0; g < 4; ++g) {
            float4 xa[2][4];   // [token i][quad j]
            #pragma unroll
            for (int i = 0; i < 2; ++i)
                #pragma unroll
                for (int j = 0; j < 4; ++j)
                    xa[i][j] = *reinterpret_cast<const float4*>(
                        &Xc[(ty + 16 * i) * XS + g * 16 + 4 * j]);
            float4 wb[4][4];   // [expert e][quad j]
            #pragma unroll
            for (int e = 0; e < 4; ++e)
                #pragma unroll
                for (int j = 0; j < 4; ++j)
                    wb[e][j] = *reinterpret_cast<const float4*>(
                        &Wc[(tx + 16 * e) * WS + g * 16 + 4 * j]);

            #pragma unroll
            for (int j = 3; j >= 0; --j) {
                #pragma unroll
                for (int i = 0; i < 2; ++i) {
                    #pragma unroll
                    for (int e = 0; e < 4; ++e) {
                        c[i][e][0] = __fadd_rn(c[i][e][0], __fmul_rn(xa[i][j].x, wb[e][j].x));
                        c[i][e][1] = __fadd_rn(c[i][e][1], __fmul_rn(xa[i][j].y, wb[e][j].y));
                        c[i][e][2] = __fadd_rn(c[i][e][2], __fmul_rn(xa[i][j].z, wb[e][j].z));
                        c[i][e][3] = __fadd_rn(c[i][e][3], __fmul_rn(xa[i][j].w, wb[e][j].w));
                    }
                }
            }
        }

        // ---- write next round's tiles into the other buffer, one barrier ----
        if (s + 1 < NR) {
            float* Xn = Xs + (cur ^ 1) * XHALF;
            float* Wn = Ws + (cur ^ 1) * WHALF;
            *reinterpret_cast<float4*>(&Xn[xw0]) = sx0;
            *reinterpret_cast<float4*>(&Xn[xw1]) = sx1;
            *reinterpret_cast<float4*>(&Wn[ww0]) = sw0;
            *reinterpret_cast<float4*>(&Wn[ww0 + 16 * WS]) = sw1;
            *reinterpret_cast<float4*>(&Wn[ww0 + 32 * WS]) = sw2;
            *reinterpret_cast<float4*>(&Wn[ww0 + 48 * WS]) = sw3;
        }
        __syncthreads();
    }

    // ---- finalize: (c0+c1)+(c2+c3), fp32 sigmoid exactly like np ----
    #pragma unroll
    for (int i = 0; i < 2; ++i) {
        #pragma unroll
        for (int e = 0; e < 4; ++e) {
            float z = __fadd_rn(__fadd_rn(c[i][e][0], c[i][e][1]),
                                __fadd_rn(c[i][e][2], c[i][e][3]));
            float ez = (float)exp(-(double)z);   // correctly-rounded fp32 exp
            float sg = __fdiv_rn(1.0f, __fadd_rn(1.0f, ez));
            Sc[(ty + 16 * i) * SCS + (tx + 16 * e)] = sg;
        }
    }
    __syncthreads();

    // ---- top-8 per token: lane == expert; each wave handles 8 tokens ----
    const int wave = t >> 6;  // 0..3
    for (int r = 0; r < 8; ++r) {
        const int tok = wave * 8 + r;
        const float sg = Sc[tok * SCS + lane];   // original fp32 score
        float rv = __fadd_rn(sg, my_bias);       // routing score
        float outw = 0.f;
        int   outi = 0;
        float ssum = 0.f;
        #pragma unroll
        for (int sel = 0; sel < TOPK; ++sel) {
            float v = rv;
            int   vi = lane;
            // 64-lane butterfly lexicographic max (ties -> lower index, = top_k)
            #pragma unroll
            for (int off = 1; off < 64; off <<= 1) {
                float ov = __shfl_xor(v, off);
                int   oi = __shfl_xor(vi, off);
                if (ov > v || (ov == v && oi < vi)) { v = ov; vi = oi; }
            }
            float cs = __shfl(sg, vi);  // un-biased score of winner
            ssum = __fadd_rn(ssum, cs);
            if (lane == sel) { outw = cs; outi = vi; }
            if (lane == vi) rv = -INFINITY;
        }
        if (lane < TOPK) {
            const size_t base = (size_t)(tok0 + tok) * TOPK + lane;
            out[base] = __fmul_rn(__fdiv_rn(outw, __fadd_rn(ssum, 1e-8f)), 2.5f);
            out[(size_t)N * TOPK + base] = (float)outi;
        }
    }
}

extern "C" void kernel_launch(void* const* d_in, const int* in_sizes, int n_in,
                              void* d_out, int out_size, void* d_ws, size_t ws_size,
                              hipStream_t stream) {
    const float* x    = (const float*)d_in[0];
    const float* w    = (const float*)d_in[1];
    const float* bias = (const float*)d_in[2];
    float* out = (float*)d_out;
    const int N = in_sizes[0] / D_DIM;  // 16384
    const int grid = N / TM;            // 512
    expert_gate_kernel<<<grid, 256, 0, stream>>>(x, w, bias, out, N);
}

// Round 5
// 318.211 us; speedup vs baseline: 1.3311x; 1.3311x over previous
//
#include <hip/hip_runtime.h>
#include <math.h>

// ExpertGate — np.einsum-bitwise replication, TM=16 occupancy + packed-fp32.
//
// CORRECTNESS CONTRACT (np SSE-einsum replication, passed R2/R3):
//   per (token, expert): 4 accumulator chains (k mod 4); k in groups of 16
//   (ascending), quads within a group processed j = 3,2,1,0; separate mul/add
//   roundings (NEVER contracted to FMA); final reduce (c0+c1)+(c2+c3);
//   sigmoid = 1/(1+exp(-z)) in fp32 with correctly-rounded fp32 exp.
//
// R4 POST-MORTEM: weights PASSED, indices failed err=35 (same as R1) — a
// single near-tie boundary flip, not a structural bug. Suspect: hipcc's
// default -ffp-contract=fast fused some __fmul_rn/__fadd_rn pairs (HIP's
// _rn builtins don't reliably block contraction). HARDENING:
//   #pragma clang fp contract(off) over the whole kernel.
// If this STILL fails with err~35 -> np reference is FMA-based (host numpy
// AVX dispatch); next step is replicating the AVX512-FMA einsum path.
//
// PERF vs R2 (162us dispatch):
//   - TM=16 -> grid 1024 -> 4 blocks/CU -> 16 waves/CU (R2: 8). Stalls (87us
//     at 8 waves, measured inversely proportional in R3) should ~halve.
//   - chains packed as 2x float2 -> v_pk_mul_f32/v_pk_add_f32 under
//     contract(off): bitwise-identical per lane, halves VALU inst count
//     (issue-limited stream: 54.6us floor -> ~27us).

#pragma clang fp contract(off)

#define D_DIM 2048
#define E_DIM 64
#define TOPK 8
#define TM 16               // tokens per block
#define BK 64               // k staged per round (4 groups of 16)
#define NR (D_DIM / BK)     // 32 rounds
#define XS 68               // row strides (floats): 16B-aligned, non-pow2
#define WS 68
#define SCS 65

typedef float v2f __attribute__((ext_vector_type(2)));

__global__ __launch_bounds__(256, 4) void expert_gate_kernel(
    const float* __restrict__ x,      // (N, 2048)
    const float* __restrict__ w,      // (64, 2048)
    const float* __restrict__ bias,   // (64,)
    float* __restrict__ out,          // N*8 weights, then N*8 indices-as-float
    int N)
{
#pragma clang fp contract(off)
    __shared__ float Xs[TM * XS];     //  4.3 KB
    __shared__ float Ws[E_DIM * WS];  // 17.4 KB
    __shared__ float Sc[TM * SCS];    //  4.2 KB   (total 25.9 KB -> 4 blocks/CU)

    const int t    = threadIdx.x;
    const int tx   = t & 15;          // experts tx + 16*e, e=0..3
    const int ty   = t >> 4;          // token (0..15)
    const int tok0 = blockIdx.x * TM;
    const int lane = t & 63;
    const float my_bias = bias[lane];

    // ---- per-thread staging addresses (hoisted) ----
    const int srow = t >> 4;          // 0..15
    const int scol = (t & 15) << 2;   // 0,4,..,60
    const float* xp = &x[(size_t)(tok0 + srow) * D_DIM + scol];
    const float* wp = &w[(size_t)srow * D_DIM + scol];
    const int xw = srow * XS + scol;
    const int ww = srow * WS + scol;

    // chains packed: c01[e] = (chain0, chain1), c23[e] = (chain2, chain3)
    v2f c01[4], c23[4];
    #pragma unroll
    for (int e = 0; e < 4; ++e) { c01[e] = (v2f)(0.f); c23[e] = (v2f)(0.f); }

    for (int s = 0; s < NR; ++s) {
        // ---- stage X tile: 16 rows x 64 floats (256 float4, 1/thread) ----
        float4 v = *reinterpret_cast<const float4*>(xp);
        xp += BK;
        *reinterpret_cast<float4*>(&Xs[xw]) = v;
        // ---- stage W tile: 64 rows x 64 floats (1024 float4, 4/thread) ----
        #pragma unroll
        for (int i = 0; i < 4; ++i) {
            float4 u = *reinterpret_cast<const float4*>(wp + i * 16 * D_DIM);
            *reinterpret_cast<float4*>(&Ws[ww + i * 16 * WS]) = u;
        }
        wp += BK;
        __syncthreads();

        // ---- compute: 4 groups of 16 k; quads within group in order 3,2,1,0
        // (R2's proven loop nest: g -> load all operands -> j desc -> e)
        #pragma unroll
        for (int g = 0; g < 4; ++g) {
            float4 xa[4];   // [quad j] of this thread's token
            #pragma unroll
            for (int j = 0; j < 4; ++j)
                xa[j] = *reinterpret_cast<const float4*>(
                    &Xs[ty * XS + g * 16 + 4 * j]);
            float4 wb[4][4];   // [expert e][quad j]
            #pragma unroll
            for (int e = 0; e < 4; ++e)
                #pragma unroll
                for (int j = 0; j < 4; ++j)
                    wb[e][j] = *reinterpret_cast<const float4*>(
                        &Ws[(tx + 16 * e) * WS + g * 16 + 4 * j]);

            #pragma unroll
            for (int j = 3; j >= 0; --j) {
                const v2f xlo = *reinterpret_cast<const v2f*>(&xa[j].x);
                const v2f xhi = *reinterpret_cast<const v2f*>(&xa[j].z);
                #pragma unroll
                for (int e = 0; e < 4; ++e) {
                    const v2f wlo = *reinterpret_cast<const v2f*>(&wb[e][j].x);
                    const v2f whi = *reinterpret_cast<const v2f*>(&wb[e][j].z);
                    // contract(off): lowers to v_pk_mul_f32 + v_pk_add_f32,
                    // per-component rounding == scalar __fmul_rn/__fadd_rn.
                    c01[e] = c01[e] + xlo * wlo;
                    c23[e] = c23[e] + xhi * whi;
                }
            }
        }
        __syncthreads();
    }

    // ---- finalize: (c0+c1)+(c2+c3), fp32 sigmoid exactly like np ----
    #pragma unroll
    for (int e = 0; e < 4; ++e) {
        float z = __fadd_rn(__fadd_rn(c01[e].x, c01[e].y),
                            __fadd_rn(c23[e].x, c23[e].y));
        float ez = (float)exp(-(double)z);   // correctly-rounded fp32 exp
        float sg = __fdiv_rn(1.0f, __fadd_rn(1.0f, ez));
        Sc[ty * SCS + (tx + 16 * e)] = sg;
    }
    __syncthreads();

    // ---- top-8 per token: lane == expert; each wave handles 4 tokens ----
    const int wave = t >> 6;  // 0..3
    for (int r = 0; r < 4; ++r) {
        const int tok = wave * 4 + r;
        const float sg = Sc[tok * SCS + lane];   // original fp32 score
        float rv = __fadd_rn(sg, my_bias);       // routing score
        float outw = 0.f;
        int   outi = 0;
        float ssum = 0.f;
        #pragma unroll
        for (int sel = 0; sel < TOPK; ++sel) {
            float vv = rv;
            int   vi = lane;
            // 64-lane butterfly lexicographic max (ties -> lower index, = top_k)
            #pragma unroll
            for (int off = 1; off < 64; off <<= 1) {
                float ov = __shfl_xor(vv, off);
                int   oi = __shfl_xor(vi, off);
                if (ov > vv || (ov == vv && oi < vi)) { vv = ov; vi = oi; }
            }
            float cs = __shfl(sg, vi);  // un-biased score of winner
            ssum = __fadd_rn(ssum, cs);
            if (lane == sel) { outw = cs; outi = vi; }
            if (lane == vi) rv = -INFINITY;
        }
        if (lane < TOPK) {
            const size_t base = (size_t)(tok0 + tok) * TOPK + lane;
            out[base] = __fmul_rn(__fdiv_rn(outw, __fadd_rn(ssum, 1e-8f)), 2.5f);
            out[(size_t)N * TOPK + base] = (float)outi;
        }
    }
}

extern "C" void kernel_launch(void* const* d_in, const int* in_sizes, int n_in,
                              void* d_out, int out_size, void* d_ws, size_t ws_size,
                              hipStream_t stream) {
    const float* x    = (const float*)d_in[0];
    const float* w    = (const float*)d_in[1];
    const float* bias = (const float*)d_in[2];
    float* out = (float*)d_out;
    const int N = in_sizes[0] / D_DIM;  // 16384
    const int grid = N / TM;            // 1024
    expert_gate_kernel<<<grid, 256, 0, stream>>>(x, w, bias, out, N);
}

// Round 7
// 280.750 us; speedup vs baseline: 1.5087x; 1.1334x over previous
//
#include <hip/hip_runtime.h>
#include <math.h>

// ExpertGate — np.einsum-bitwise replication; TM=32 + T14 reg-prefetch +
// forced packed-fp32 math (v_pk_mul_f32 / v_pk_add_f32 inline asm).
// (Identical resubmit of the round-6 kernel: that bench died in the broker
// before producing any kernel signal — "container failed twice".)
//
// CORRECTNESS CONTRACT (passed R2/R3/R5): per (token, expert):
//   - 4 accumulator chains (k mod 4); k in groups of 16 (ascending);
//     quads within a group processed j = 3,2,1,0
//   - separate mul/add roundings, NEVER contracted ( #pragma clang fp
//     contract(off) — R4 failed without it; inline asm is inherently immune )
//   - chains packed as float2 components: per-component VOP3P rounding is
//     identical to the scalar op, and each chain keeps its exact op order
//   - final reduce (c0+c1)+(c2+c3); sigmoid = 1/(1+exp(-z)) fp32 with
//     correctly-rounded fp32 exp; top-8 ties -> lower index
//
// R5 POST-MORTEM: clang did NOT emit v_pk_* for float2 arithmetic (VALU-busy
// time unchanged ~73us) and TM=16 doubled per-CU W-staging work (162->190us
// despite 2x occupancy). R2's occupancy was GRID-limited, not resource-limited.
// THIS ROUND: back to TM=32 (grid 512, 2 tok x 4 exp per thread = best LDS
// amortization), stall fix INSIDE the block:
//   - T14: issue next round's 6 global float4 loads into registers BEFORE
//     compute (latency hides under ~2000cy of pk-math), ds_write after the
//     read barrier, single LDS buffer (34.4 KB — R3's dbuf occupancy mistake
//     not repeated)
//   - inline-asm v_pk_mul_f32/v_pk_add_f32 halves the mandatory VALU stream
//     (54.6 -> 27.3us chip floor)

#pragma clang fp contract(off)

#define D_DIM 2048
#define E_DIM 64
#define TOPK 8
#define TM 32               // tokens per block
#define BK 64               // k staged per round (4 groups of 16)
#define NR (D_DIM / BK)     // 32 rounds
#define XS 68               // row strides (floats): 16B-aligned, non-pow2
#define WS 68
#define SCS 65

typedef float v2f __attribute__((ext_vector_type(2)));

static __device__ __forceinline__ v2f pk_mul(v2f a, v2f b) {
    v2f d;
    asm("v_pk_mul_f32 %0, %1, %2" : "=v"(d) : "v"(a), "v"(b));
    return d;
}
static __device__ __forceinline__ v2f pk_add(v2f a, v2f b) {
    v2f d;
    asm("v_pk_add_f32 %0, %1, %2" : "=v"(d) : "v"(a), "v"(b));
    return d;
}

__global__ __launch_bounds__(256, 2) void expert_gate_kernel(
    const float* __restrict__ x,      // (N, 2048)
    const float* __restrict__ w,      // (64, 2048)
    const float* __restrict__ bias,   // (64,)
    float* __restrict__ out,          // N*8 weights, then N*8 indices-as-float
    int N)
{
#pragma clang fp contract(off)
    __shared__ float Xs[TM * XS];     //  8.7 KB
    __shared__ float Ws[E_DIM * WS];  // 17.4 KB
    __shared__ float Sc[TM * SCS];    //  8.3 KB  (34.4 KB total)

    const int t    = threadIdx.x;
    const int tx   = t & 15;          // experts tx + 16*e, e=0..3
    const int ty   = t >> 4;          // token rows ty and ty+16
    const int tok0 = blockIdx.x * TM;
    const int lane = t & 63;
    const float my_bias = bias[lane];

    // ---- per-thread staging addresses (hoisted) ----
    const int srow = t >> 4;          // 0..15
    const int scol = (t & 15) << 2;   // 0,4,..,60
    const float* xp0 = &x[(size_t)(tok0 + srow) * D_DIM + scol];
    const float* xp1 = &x[(size_t)(tok0 + 16 + srow) * D_DIM + scol];
    const float* wp  = &w[(size_t)srow * D_DIM + scol];
    const int xw0 = srow * XS + scol;
    const int xw1 = (srow + 16) * XS + scol;
    const int ww0 = srow * WS + scol;

    // c01[i][e] = (chain0, chain1), c23[i][e] = (chain2, chain3)
    v2f c01[2][4], c23[2][4];
    #pragma unroll
    for (int i = 0; i < 2; ++i)
        #pragma unroll
        for (int e = 0; e < 4; ++e) { c01[i][e] = (v2f)(0.f); c23[i][e] = (v2f)(0.f); }

    // ---- prologue: stage round 0 ----
    float4 sx0 = *reinterpret_cast<const float4*>(xp0);
    float4 sx1 = *reinterpret_cast<const float4*>(xp1);
    float4 sw0 = *reinterpret_cast<const float4*>(wp);
    float4 sw1 = *reinterpret_cast<const float4*>(wp + 16 * D_DIM);
    float4 sw2 = *reinterpret_cast<const float4*>(wp + 32 * D_DIM);
    float4 sw3 = *reinterpret_cast<const float4*>(wp + 48 * D_DIM);
    xp0 += BK; xp1 += BK; wp += BK;
    *reinterpret_cast<float4*>(&Xs[xw0]) = sx0;
    *reinterpret_cast<float4*>(&Xs[xw1]) = sx1;
    *reinterpret_cast<float4*>(&Ws[ww0]) = sw0;
    *reinterpret_cast<float4*>(&Ws[ww0 + 16 * WS]) = sw1;
    *reinterpret_cast<float4*>(&Ws[ww0 + 32 * WS]) = sw2;
    *reinterpret_cast<float4*>(&Ws[ww0 + 48 * WS]) = sw3;
    __syncthreads();

    for (int s = 0; s < NR; ++s) {
        // ---- T14 issue-early: next round's global loads (hide under compute)
        if (s + 1 < NR) {
            sx0 = *reinterpret_cast<const float4*>(xp0);
            sx1 = *reinterpret_cast<const float4*>(xp1);
            sw0 = *reinterpret_cast<const float4*>(wp);
            sw1 = *reinterpret_cast<const float4*>(wp + 16 * D_DIM);
            sw2 = *reinterpret_cast<const float4*>(wp + 32 * D_DIM);
            sw3 = *reinterpret_cast<const float4*>(wp + 48 * D_DIM);
            xp0 += BK; xp1 += BK; wp += BK;
        }

        // ---- compute round s: 4 groups of 16 k; quads j = 3,2,1,0 ----
        #pragma unroll
        for (int g = 0; g < 4; ++g) {
            float4 xa[2][4];   // [token i][quad j]
            #pragma unroll
            for (int i = 0; i < 2; ++i)
                #pragma unroll
                for (int j = 0; j < 4; ++j)
                    xa[i][j] = *reinterpret_cast<const float4*>(
                        &Xs[(ty + 16 * i) * XS + g * 16 + 4 * j]);
            float4 wb[4][4];   // [expert e][quad j]
            #pragma unroll
            for (int e = 0; e < 4; ++e)
                #pragma unroll
                for (int j = 0; j < 4; ++j)
                    wb[e][j] = *reinterpret_cast<const float4*>(
                        &Ws[(tx + 16 * e) * WS + g * 16 + 4 * j]);

            #pragma unroll
            for (int j = 3; j >= 0; --j) {
                #pragma unroll
                for (int i = 0; i < 2; ++i) {
                    const v2f xlo = *reinterpret_cast<const v2f*>(&xa[i][j].x);
                    const v2f xhi = *reinterpret_cast<const v2f*>(&xa[i][j].z);
                    #pragma unroll
                    for (int e = 0; e < 4; ++e) {
                        const v2f wlo = *reinterpret_cast<const v2f*>(&wb[e][j].x);
                        const v2f whi = *reinterpret_cast<const v2f*>(&wb[e][j].z);
                        c01[i][e] = pk_add(c01[i][e], pk_mul(xlo, wlo));
                        c23[i][e] = pk_add(c23[i][e], pk_mul(xhi, whi));
                    }
                }
            }
        }

        __syncthreads();   // all reads of round s done
        // ---- T14 write-late: next round's tiles into the (single) buffer ----
        if (s + 1 < NR) {
            *reinterpret_cast<float4*>(&Xs[xw0]) = sx0;
            *reinterpret_cast<float4*>(&Xs[xw1]) = sx1;
            *reinterpret_cast<float4*>(&Ws[ww0]) = sw0;
            *reinterpret_cast<float4*>(&Ws[ww0 + 16 * WS]) = sw1;
            *reinterpret_cast<float4*>(&Ws[ww0 + 32 * WS]) = sw2;
            *reinterpret_cast<float4*>(&Ws[ww0 + 48 * WS]) = sw3;
        }
        __syncthreads();   // writes visible
    }

    // ---- finalize: (c0+c1)+(c2+c3), fp32 sigmoid exactly like np ----
    #pragma unroll
    for (int i = 0; i < 2; ++i) {
        #pragma unroll
        for (int e = 0; e < 4; ++e) {
            float z = __fadd_rn(__fadd_rn(c01[i][e].x, c01[i][e].y),
                                __fadd_rn(c23[i][e].x, c23[i][e].y));
            float ez = (float)exp(-(double)z);   // correctly-rounded fp32 exp
            float sg = __fdiv_rn(1.0f, __fadd_rn(1.0f, ez));
            Sc[(ty + 16 * i) * SCS + (tx + 16 * e)] = sg;
        }
    }
    __syncthreads();

    // ---- top-8 per token: lane == expert; each wave handles 8 tokens ----
    const int wave = t >> 6;  // 0..3
    for (int r = 0; r < 8; ++r) {
        const int tok = wave * 8 + r;
        const float sg = Sc[tok * SCS + lane];   // original fp32 score
        float rv = __fadd_rn(sg, my_bias);       // routing score
        float outw = 0.f;
        int   outi = 0;
        float ssum = 0.f;
        #pragma unroll
        for (int sel = 0; sel < TOPK; ++sel) {
            float vv = rv;
            int   vi = lane;
            // 64-lane butterfly lexicographic max (ties -> lower index, = top_k)
            #pragma unroll
            for (int off = 1; off < 64; off <<= 1) {
                float ov = __shfl_xor(vv, off);
                int   oi = __shfl_xor(vi, off);
                if (ov > vv || (ov == vv && oi < vi)) { vv = ov; vi = oi; }
            }
            float cs = __shfl(sg, vi);  // un-biased score of winner
            ssum = __fadd_rn(ssum, cs);
            if (lane == sel) { outw = cs; outi = vi; }
            if (lane == vi) rv = -INFINITY;
        }
        if (lane < TOPK) {
            const size_t base = (size_t)(tok0 + tok) * TOPK + lane;
            out[base] = __fmul_rn(__fdiv_rn(outw, __fadd_rn(ssum, 1e-8f)), 2.5f);
            out[(size_t)N * TOPK + base] = (float)outi;
        }
    }
}

extern "C" void kernel_launch(void* const* d_in, const int* in_sizes, int n_in,
                              void* d_out, int out_size, void* d_ws, size_t ws_size,
                              hipStream_t stream) {
    const float* x    = (const float*)d_in[0];
    const float* w    = (const float*)d_in[1];
    const float* bias = (const float*)d_in[2];
    float* out = (float*)d_out;
    const int N = in_sizes[0] / D_DIM;  // 16384
    const int grid = N / TM;            // 512
    expert_gate_kernel<<<grid, 256, 0, stream>>>(x, w, bias, out, N);
}